// Round 7
// baseline (1174.754 us; speedup 1.0000x reference)
//
#include <hip/hip_runtime.h>
#include <cstdint>
#include <cstddef>

// Problem constants: B=32, L=2048, D=1024, E=2048
#define B_ 32
#define L_ 2048
#define D_ 1024
#define E_ 2048
// GEMM view: M = B*L = 65536 rows (b,l), N = D = 1024, K = E = 2048

typedef __attribute__((ext_vector_type(8))) short short8;
typedef __attribute__((ext_vector_type(16))) float f32x16;
typedef __attribute__((ext_vector_type(4))) unsigned int uint4v;

// pack two fp32 -> bf16x2 (round-half-up: add 0x8000, take hi16)
__device__ __forceinline__ unsigned int pack_bf16_2(float lo, float hi) {
  unsigned int ul = __builtin_bit_cast(unsigned int, lo) + 0x8000u;
  unsigned int uh = __builtin_bit_cast(unsigned int, hi) + 0x8000u;
  return (ul >> 16) | (uh & 0xFFFF0000u);
}

// single-instruction pack (RNE)
__device__ __forceinline__ unsigned int cvt_pk_bf16(float lo, float hi) {
  unsigned int r;
  asm("v_cvt_pk_bf16_f32 %0, %1, %2" : "=v"(r) : "v"(lo), "v"(hi));
  return r;
}

__device__ __forceinline__ float fast_tanh(float x) {
  float e = __expf(2.0f * x);
  return 1.0f - 2.0f / (e + 1.0f);
}

// ---------------- kernel 1: s[b][i] = sum_d dec[b][d] * Ws[i][d] ------------
__global__ __launch_bounds__(256) void k_s(const float* __restrict__ dec,
                                           const float* __restrict__ Ws,
                                           float* __restrict__ s) {
  int wid = threadIdx.x >> 6, lane = threadIdx.x & 63;
  int out = blockIdx.x * 4 + wid;            // 0..32767
  int b = out >> 10, i = out & 1023;
  const float* dr = dec + b * D_;
  const float* wr = Ws + (size_t)i * D_;
  float acc = 0.f;
#pragma unroll
  for (int c = 0; c < 4; ++c) {
    int d0 = c * 256 + lane * 4;
    float4 x = *(const float4*)(dr + d0);
    float4 w = *(const float4*)(wr + d0);
    acc += x.x * w.x + x.y * w.y + x.z * w.z + x.w * w.w;
  }
#pragma unroll
  for (int off = 32; off >= 1; off >>= 1) acc += __shfl_xor(acc, off, 64);
  if (lane == 0) s[out] = acc;
}

// ---------------- kernel 2: W_h fp32 -> bf16 (2M elements) ------------------
__global__ __launch_bounds__(256) void k_cvt(const float* __restrict__ src,
                                             unsigned short* __restrict__ dst) {
  size_t i = ((size_t)blockIdx.x * 256 + threadIdx.x) * 8;
  float4 a = *(const float4*)(src + i);
  float4 b = *(const float4*)(src + i + 4);
  uint4v p;
  p.x = pack_bf16_2(a.x, a.y);
  p.y = pack_bf16_2(a.z, a.w);
  p.z = pack_bf16_2(b.x, b.y);
  p.w = pack_bf16_2(b.z, b.w);
  *(uint4v*)(dst + i) = p;
}

// ---------------- kernel 3: fused GEMM + tanh + v-dot -----------------------
// scores[m] = sum_n v[n] * tanh(s[b][n] + sum_k enc[m][k]*Whb[n][k]),  m=(b,l)
// Block tile 128(M)x128(N), BK=32; 256 threads = 4 waves (2M x 2N).
//
// R6 diagnosis: FETCH=503MB = enc read once (XCD/L2 reuse WORKS; HBM is at
// its minimum), but all pipes <30% -> occupancy/latency-bound at 2 blocks/CU
// (64 KB LDS limiter, 2 waves/SIMD). Fix: BK 64->32 halves LDS to 32 KB ->
// 3 blocks/CU (launch_bounds(256,3), 12 waves/CU). Same verified
// single-barrier pipelined structure, prefetch distances, swizzle family.
//
// LDS layout (A and B identical, BK=32): 32 lines x 256 B; line = 4 rows x
// 64 B; 16x 16B units, unit u of row holds k in [8u,8u+8); u_log = r2*4 + u,
// stored at (u_log ^ (line&15))*16. Frag reads (u_log = r2*4 + ks*2 + h) are
// conflict-free per 8-lane line-group.
__global__ __launch_bounds__(256, 3) void k_gemm(const float* __restrict__ enc,
                                                 const unsigned short* __restrict__ whb,
                                                 const float* __restrict__ sbias,
                                                 const float* __restrict__ vvec,
                                                 float* __restrict__ scores) {
  __shared__ alignas(16) unsigned short As[2][32 * 128];  // 2 x 8 KB bf16
  __shared__ alignas(16) unsigned short Bs[2][32 * 128];  // 2 x 8 KB bf16

  const int tid = threadIdx.x;
  const int wid = tid >> 6;        // 0..3
  const int lane = tid & 63;
  const int wm = wid >> 1;         // wave row (M)
  const int wn = wid & 1;          // wave col (N)

  // XCD swizzle: all 8 N-tiles of one M-tile share flat%8 -> same XCD L2.
  const int flat = blockIdx.x;
  const int nt = (flat >> 3) & 7;
  const int mt = (flat & 7) | ((flat >> 6) << 3);
  const int m_base = mt * 128, n_base = nt * 128;
  const int b_idx = m_base >> 11;  // 128 | 2048 -> b uniform per block

  // --- A staging: row = tid>>1; granule g = 2c + (tid&1) (32B thread-pairs) --
  const int tOdd = tid & 1;
  const float* gAr = enc + (size_t)(m_base + (tid >> 1)) * E_ + tOdd * 4;
  const int sLine = tid >> 3;                 // row>>2
  const int sR2 = (tid >> 1) & 3;             // row&3
  int aWoff[4];
#pragma unroll
  for (int c = 0; c < 4; ++c)
    aWoff[c] = sLine * 256 + (((sR2 * 4 + c) ^ (sLine & 15)) << 4) + tOdd * 8;

  // --- B staging: n = tid>>1; unit u = 2j + (tid&1) (32B thread-pairs) ---
  const unsigned short* gBr = whb + (size_t)(n_base + (tid >> 1)) * E_ + tOdd * 8;
  int bWoff[2];
#pragma unroll
  for (int j = 0; j < 2; ++j)
    bWoff[j] = sLine * 256 + (((sR2 * 4 + 2 * j + tOdd) ^ (sLine & 15)) << 4);

  // --- fragment read addressing (byte offsets, swizzle folded in) ---
  const int col = lane & 31;
  const int h = lane >> 5;
  int aRd[2][2], bRd[2][2];
#pragma unroll
  for (int mi = 0; mi < 2; ++mi)
#pragma unroll
    for (int ks = 0; ks < 2; ++ks) {
      int line = wm * 16 + mi * 8 + (col >> 2);
      int ul = (col & 3) * 4 + ks * 2 + h;
      aRd[mi][ks] = line * 256 + ((ul ^ (line & 15)) << 4);
    }
#pragma unroll
  for (int ni = 0; ni < 2; ++ni)
#pragma unroll
    for (int ks = 0; ks < 2; ++ks) {
      int line = wn * 16 + ni * 8 + (col >> 2);
      int ul = (col & 3) * 4 + ks * 2 + h;
      bRd[ni][ks] = line * 256 + ((ul ^ (line & 15)) << 4);
    }

  f32x16 acc[2][2] = {};
  float4 rAv0[4], rAv1[4];   // A prefetch sets (distance 2)
  uint4v rBv[2];             // B prefetch set (distance 1)

  // --- prologue: B(0), A(0)->set0, A(1)->set1; write buf0; B(1), A(2) ---
#pragma unroll
  for (int j = 0; j < 2; ++j)
    rBv[j] = *(const uint4v*)(gBr + j * 16);
#pragma unroll
  for (int c = 0; c < 4; ++c)
    rAv0[c] = *(const float4*)(gAr + c * 8);
#pragma unroll
  for (int c = 0; c < 4; ++c)
    rAv1[c] = *(const float4*)(gAr + c * 8 + 32);
  {
#pragma unroll
    for (int c = 0; c < 4; ++c) {
      uint2 qa;
      qa.x = cvt_pk_bf16(rAv0[c].x, rAv0[c].y);
      qa.y = cvt_pk_bf16(rAv0[c].z, rAv0[c].w);
      *(uint2*)((char*)As + aWoff[c]) = qa;
    }
#pragma unroll
    for (int j = 0; j < 2; ++j)
      *(uint4v*)((char*)Bs + bWoff[j]) = rBv[j];
  }
#pragma unroll
  for (int j = 0; j < 2; ++j)
    rBv[j] = *(const uint4v*)(gBr + j * 16 + 32);          // B(1)
#pragma unroll
  for (int c = 0; c < 4; ++c)
    rAv0[c] = *(const float4*)(gAr + c * 8 + 64);          // A(2)
  asm volatile("s_waitcnt lgkmcnt(0)" ::: "memory");
  __builtin_amdgcn_sched_barrier(0);
  __builtin_amdgcn_s_barrier();
  __builtin_amdgcn_sched_barrier(0);

  // Iter t (KK = 32t): pack tile t+1 from RA/rBv into buf RD^8192, issue
  // B(t+2) then A(t+3), compute tile t from buf RD, lgkm+barrier.
#define GSTEP(KK, RA, DO_PACK, DO_A, DO_B, RD)                              \
  {                                                                         \
    if (DO_PACK) {                                                          \
      _Pragma("unroll") for (int c = 0; c < 4; ++c) {                       \
        uint2 qa;                                                           \
        qa.x = cvt_pk_bf16(RA[c].x, RA[c].y);                               \
        qa.y = cvt_pk_bf16(RA[c].z, RA[c].w);                               \
        *(uint2*)((char*)As + ((RD) ^ 8192) + aWoff[c]) = qa;               \
      }                                                                     \
      _Pragma("unroll") for (int j = 0; j < 2; ++j)                         \
        *(uint4v*)((char*)Bs + ((RD) ^ 8192) + bWoff[j]) = rBv[j];          \
    }                                                                       \
    if (DO_B) {                                                             \
      _Pragma("unroll") for (int j = 0; j < 2; ++j)                         \
        rBv[j] = *(const uint4v*)(gBr + j * 16 + (KK) + 64);                \
    }                                                                       \
    if (DO_A) {                                                             \
      _Pragma("unroll") for (int c = 0; c < 4; ++c)                         \
        RA[c] = *(const float4*)(gAr + c * 8 + (KK) + 96);                  \
    }                                                                       \
    _Pragma("unroll") for (int ks = 0; ks < 2; ++ks) {                      \
      short8 bf[2], af[2];                                                  \
      _Pragma("unroll") for (int ni = 0; ni < 2; ++ni)                      \
        bf[ni] = *(const short8*)((char*)Bs + (RD) + bRd[ni][ks]);          \
      _Pragma("unroll") for (int mi = 0; mi < 2; ++mi)                      \
        af[mi] = *(const short8*)((char*)As + (RD) + aRd[mi][ks]);          \
      _Pragma("unroll") for (int mi = 0; mi < 2; ++mi)                      \
        _Pragma("unroll") for (int ni = 0; ni < 2; ++ni)                    \
          acc[mi][ni] = __builtin_amdgcn_mfma_f32_32x32x16_bf16(            \
              af[mi], bf[ni], acc[mi][ni], 0, 0, 0);                        \
    }                                                                       \
    asm volatile("s_waitcnt lgkmcnt(0)" ::: "memory");                      \
    __builtin_amdgcn_sched_barrier(0);                                      \
    __builtin_amdgcn_s_barrier();                                           \
    __builtin_amdgcn_sched_barrier(0);                                      \
  }

  // main loop t = 0..59 (30 pairs), peeled tail t = 60..63
  for (int kk = 0; kk < 1920; kk += 64) {
    GSTEP(kk, rAv1, 1, 1, 1, 0);
    GSTEP(kk + 32, rAv0, 1, 1, 1, 8192);
  }
  GSTEP(1920, rAv1, 1, 1, 1, 0);      // t=60: pack 61, load B62, A63
  GSTEP(1952, rAv0, 1, 0, 1, 8192);   // t=61: pack 62, load B63
  GSTEP(1984, rAv1, 1, 0, 0, 0);      // t=62: pack 63
  GSTEP(2016, rAv0, 0, 0, 0, 8192);   // t=63: compute only
#undef GSTEP

  // --- epilogue: partial = sum over this wave's 64 n of v[n]*tanh(s+h) ---
  // 32x32 C/D layout (m74/m101): col = lane&31, row = (reg&3)+8*(reg>>2)+4*(lane>>5)
  float vv[2], sv[2];
#pragma unroll
  for (int ni = 0; ni < 2; ++ni) {
    int n = n_base + wn * 64 + ni * 32 + col;
    vv[ni] = vvec[n];
    sv[ni] = sbias[b_idx * D_ + n];
  }
#pragma unroll
  for (int mi = 0; mi < 2; ++mi) {
#pragma unroll
    for (int reg = 0; reg < 16; ++reg) {
      float sum = 0.f;
#pragma unroll
      for (int ni = 0; ni < 2; ++ni)
        sum += vv[ni] * fast_tanh(sv[ni] + acc[mi][ni][reg]);
      sum += __shfl_xor(sum, 1, 64);
      sum += __shfl_xor(sum, 2, 64);
      sum += __shfl_xor(sum, 4, 64);
      sum += __shfl_xor(sum, 8, 64);
      sum += __shfl_xor(sum, 16, 64);
      if (col == 0)
        atomicAdd(&scores[m_base + wm * 64 + mi * 32 + (reg & 3) + 8 * (reg >> 2) + h * 4], sum);
    }
  }
}

// ---------------- kernel 4: softmax over L per b (in-place) -----------------
__global__ __launch_bounds__(256) void k_softmax(float* __restrict__ sc) {
  int b = blockIdx.x, tid = threadIdx.x;
  int lane = tid & 63, wid = tid >> 6;
  float* row = sc + (size_t)b * L_;
  float vals[8];
  float mx = -1e30f;
#pragma unroll
  for (int j = 0; j < 8; ++j) { vals[j] = row[tid + j * 256]; mx = fmaxf(mx, vals[j]); }
#pragma unroll
  for (int off = 32; off >= 1; off >>= 1) mx = fmaxf(mx, __shfl_xor(mx, off, 64));
  __shared__ float redm[4], reds[4];
  if (lane == 0) redm[wid] = mx;
  __syncthreads();
  mx = fmaxf(fmaxf(redm[0], redm[1]), fmaxf(redm[2], redm[3]));
  float sum = 0.f;
#pragma unroll
  for (int j = 0; j < 8; ++j) { vals[j] = __expf(vals[j] - mx); sum += vals[j]; }
#pragma unroll
  for (int off = 32; off >= 1; off >>= 1) sum += __shfl_xor(sum, off, 64);
  if (lane == 0) reds[wid] = sum;
  __syncthreads();
  sum = reds[0] + reds[1] + reds[2] + reds[3];
  float inv = 1.0f / sum;
#pragma unroll
  for (int j = 0; j < 8; ++j) row[tid + j * 256] = vals[j] * inv;
}

// ---------------- kernel 5a: ctx partials (NO atomics) ----------------------
// partial[c][b][e], c = 16 l-chunks of 128 rows. Aliased onto whb (dead after
// k_gemm; k_cvt regenerates it every launch -> replay-safe).
__global__ __launch_bounds__(256) void k_ctx_p(const float* __restrict__ enc,
                                               const float* __restrict__ attn,
                                               float* __restrict__ partial) {
  int b = blockIdx.y;
  int lc = blockIdx.x >> 1;        // 0..15, 128 rows each
  int eh = blockIdx.x & 1;         // E half
  int t = threadIdx.x;
  __shared__ float aw[128];
  if (t < 128) aw[t] = attn[(size_t)b * L_ + lc * 128 + t];
  __syncthreads();
  const float* base = enc + ((size_t)b * L_ + (size_t)lc * 128) * E_ + eh * 1024;
  float4 a0 = make_float4(0.f, 0.f, 0.f, 0.f);
#pragma unroll 8
  for (int l = 0; l < 128; ++l) {
    float w = aw[l];
    float4 x0 = *(const float4*)(base + (size_t)l * E_ + t * 4);
    a0.x += w * x0.x; a0.y += w * x0.y; a0.z += w * x0.z; a0.w += w * x0.w;
  }
  *(float4*)(partial + ((size_t)(lc * 32 + b) * E_) + eh * 1024 + t * 4) = a0;
}

// ---------------- kernel 5b: reduce partials -> ctx -------------------------
__global__ __launch_bounds__(256) void k_ctx_r(const float* __restrict__ partial,
                                               float* __restrict__ ctx) {
  int idx = blockIdx.x * 256 + threadIdx.x;   // 0..16383
  int b = idx >> 9;                            // 0..31
  int e4 = idx & 511;                          // float4 index within E
  float4 s = make_float4(0.f, 0.f, 0.f, 0.f);
#pragma unroll
  for (int c = 0; c < 16; ++c) {
    float4 p = *(const float4*)(partial + ((size_t)(c * 32 + b) * E_) + e4 * 4);
    s.x += p.x; s.y += p.y; s.z += p.z; s.w += p.w;
  }
  *(float4*)(ctx + (size_t)b * E_ + e4 * 4) = s;
}

extern "C" void kernel_launch(void* const* d_in, const int* in_sizes, int n_in,
                              void* d_out, int out_size, void* d_ws, size_t ws_size,
                              hipStream_t stream) {
  const float* dec = (const float*)d_in[0];  // [32,1024]
  const float* enc = (const float*)d_in[1];  // [32,2048,2048]
  const float* Ws  = (const float*)d_in[2];  // [1024,1024]
  const float* Wh  = (const float*)d_in[3];  // [1024,2048]
  const float* v   = (const float*)d_in[4];  // [1024]

  float* ctx  = (float*)d_out;                   // [32,2048]
  float* attn = (float*)d_out + B_ * E_;         // [32,2048]; also scores scratch

  // workspace: W_h bf16 (4 MB; reused as ctx partials after k_gemm) + s (128KB)
  unsigned short* whb = (unsigned short*)d_ws;
  float* partial = (float*)d_ws;                 // alias, 16*32*2048 f32 = 4 MB
  float* sbuf = (float*)((char*)d_ws + (size_t)D_ * E_ * sizeof(unsigned short));

  // zero scores (accumulated via atomics); ctx is plain-stored by k_ctx_r
  hipMemsetAsync(d_out, 0, (size_t)out_size * sizeof(float), stream);

  k_s<<<dim3((B_ * D_) / 4), dim3(256), 0, stream>>>(dec, Ws, sbuf);
  k_cvt<<<dim3((D_ * E_) / (256 * 8)), dim3(256), 0, stream>>>(Wh, whb);
  k_gemm<<<dim3((B_ * L_ / 128) * (D_ / 128)), dim3(256), 0, stream>>>(enc, whb, sbuf, v, attn);
  k_softmax<<<dim3(B_), dim3(256), 0, stream>>>(attn);
  k_ctx_p<<<dim3(32, B_), dim3(256), 0, stream>>>(enc, attn, partial);
  k_ctx_r<<<dim3((B_ * E_) / (256 * 4)), dim3(256), 0, stream>>>(partial, ctx);
}